// Round 8
// baseline (230.246 us; speedup 1.0000x reference)
//
#include <hip/hip_runtime.h>
#include <math.h>

#define B_ROWS 8192
#define NU 512
#define FEATS 64
#define RPB 8      // rows per block (= waves per block)
#define TOPK_K 8

typedef unsigned long long ull;
typedef unsigned short ushort8 __attribute__((ext_vector_type(8)));
typedef float f32x2 __attribute__((ext_vector_type(2)));

// xor-1 / xor-2 lane exchange via DPP quad_perm (VALU pipe, no DS)
template <int CTRL>
__device__ __forceinline__ ull dpp_u64(ull x) {
  int lo = (int)(unsigned)(x & 0xffffffffULL);
  int hi = (int)(unsigned)(x >> 32);
  lo = __builtin_amdgcn_update_dpp(lo, lo, CTRL, 0xf, 0xf, true);
  hi = __builtin_amdgcn_update_dpp(hi, hi, CTRL, 0xf, 0xf, true);
  return ((ull)(unsigned)hi << 32) | (ull)(unsigned)lo;
}

__device__ __forceinline__ ull bperm_u64(int addr, ull x) {
  int lo = (int)(unsigned)(x & 0xffffffffULL);
  int hi = (int)(unsigned)(x >> 32);
  lo = __builtin_amdgcn_ds_bpermute(addr, lo);
  hi = __builtin_amdgcn_ds_bpermute(addr, hi);
  return ((ull)(unsigned)hi << 32) | (ull)(unsigned)lo;
}

// compare-exchange: after call, (a,b) ordered ascending iff asc
__device__ __forceinline__ void ce(ull& a, ull& b, bool asc) {
  const bool lt = a < b;
  const bool sw = (lt != asc);
  const ull t = sw ? b : a;
  b = sw ? a : b;
  a = t;
}

// cross-lane pass: lane-xor M, merge-size direction bit KB = K>>3
template <unsigned M, unsigned KB>
__device__ __forceinline__ void cross_t(ull v[8], unsigned lane, int addr) {
  const bool asc = ((lane & KB) == 0u);
  const bool takeMin = (((lane & M) == 0u) == asc);
#pragma unroll
  for (int i = 0; i < 8; ++i) {
    ull o;
    if constexpr (M == 1)      o = dpp_u64<0xB1>(v[i]);   // quad_perm [1,0,3,2]
    else if constexpr (M == 2) o = dpp_u64<0x4E>(v[i]);   // quad_perm [2,3,0,1]
    else                       o = bperm_u64(addr, v[i]);
    const bool keep = ((v[i] < o) == takeMin);
    v[i] = keep ? v[i] : o;
  }
}

// one bitonic merge stage of size K (16..512), fully compile-time unrolled
template <unsigned K>
__device__ __forceinline__ void stage_t(ull v[8], unsigned lane,
                                        int a4, int a8, int a16, int a32) {
  constexpr unsigned KB = (K >> 3);
  if constexpr (K >= 512) cross_t<32, KB>(v, lane, a32);
  if constexpr (K >= 256) cross_t<16, KB>(v, lane, a16);
  if constexpr (K >= 128) cross_t<8,  KB>(v, lane, a8);
  if constexpr (K >= 64)  cross_t<4,  KB>(v, lane, a4);
  if constexpr (K >= 32)  cross_t<2,  KB>(v, lane, 0);
  cross_t<1, KB>(v, lane, 0);
  const bool asc = ((lane & KB) == 0u);
  ce(v[0], v[4], asc); ce(v[1], v[5], asc); ce(v[2], v[6], asc); ce(v[3], v[7], asc);
  ce(v[0], v[2], asc); ce(v[1], v[3], asc); ce(v[4], v[6], asc); ce(v[5], v[7], asc);
  ce(v[0], v[1], asc); ce(v[2], v[3], asc); ce(v[4], v[5], asc); ce(v[6], v[7], asc);
}

// Evidence ledger:
//  r1/r6: remat'd c + 8 waves/SIMD = 57.6 us baseline. r6's f32x2 packing cut
//      VALU-issue 39->29 us, wall flat => memory-pipe (c-load) bound.
//  r2/r5/r7: ALL register-pinning variants lose (volatile pins serialize VMEM
//      -> 104 us; non-volatile pins shrink the allocator to 40 VGPR and kill
//      load batching -> 105 us). NEVER pin c in registers on this target.
//  r3: >64 live regs at 512 threads spills to scratch (+30 MB HBM) -> 65 us.
//  => This version: 2-row tile with NO pins. The compiler remats c per
//     use-site; 2-row bodies have 64 use-sites instead of 128, so c-loads
//     halve naturally while the scheduler keeps full freedom to batch.
//     Accumulators ra2+rb2 = 32 regs, peak live ~55 -> no spill expected.
__global__ __launch_bounds__(512)
void lcm_kernel(const float* __restrict__ x, const float* __restrict__ c,
                float* __restrict__ out) {
#pragma clang fp contract(off)
  __shared__ ull keys[RPB * NU];                          // 32 KB
  __shared__ __align__(16) unsigned short rks[RPB * NU];  // 8 KB (40 KB total -> 4 blocks/CU)

  const int t = threadIdx.x;
  const int r0 = blockIdx.x * RPB;

  // ---- distances: 2-row tiles, f32x2-packed arithmetic, no pins ----
  {
    const int n = t;
    const float4* c4 = (const float4*)c + (size_t)n * 16;
    float* o_d = out;

#pragma unroll
    for (int h = 0; h < 4; ++h) {
      const float* __restrict__ xa = x + (size_t)(r0 + 2 * h + 0) * FEATS;  // uniform
      const float* __restrict__ xb = x + (size_t)(r0 + 2 * h + 1) * FEATS;  // uniform
      // ra2[m]/rb2[m] = (rr[2m], rr[2m+1]) of the reference's rr[16], rows A/B
      f32x2 ra2[8], rb2[8];
#pragma unroll
      for (int k = 0; k < 4; ++k) {
#pragma unroll
        for (int q = 0; q < 4; ++q) {
          const float4 cv = c4[k * 4 + q];
          const float4 xva = *(const float4*)(xa + 16 * k + 4 * q);
          const float4 xvb = *(const float4*)(xb + 16 * k + 4 * q);
          f32x2 clo, chi, alo, ahi, blo, bhi;
          clo[0] = cv.x;  clo[1] = cv.y;  chi[0] = cv.z;  chi[1] = cv.w;
          alo[0] = xva.x; alo[1] = xva.y; ahi[0] = xva.z; ahi[1] = xva.w;
          blo[0] = xvb.x; blo[1] = xvb.y; bhi[0] = xvb.z; bhi[1] = xvb.w;
          const f32x2 dalo = alo - clo;   // v_pk ops, IEEE per element
          const f32x2 dahi = ahi - chi;
          const f32x2 dblo = blo - clo;
          const f32x2 dbhi = bhi - chi;
          if (k == 0) {
            ra2[q * 2 + 0] = dalo * dalo; ra2[q * 2 + 1] = dahi * dahi;
            rb2[q * 2 + 0] = dblo * dblo; rb2[q * 2 + 1] = dbhi * dbhi;
          } else {
            ra2[q * 2 + 0] = ra2[q * 2 + 0] + dalo * dalo;
            ra2[q * 2 + 1] = ra2[q * 2 + 1] + dahi * dahi;
            rb2[q * 2 + 0] = rb2[q * 2 + 0] + dblo * dblo;
            rb2[q * 2 + 1] = rb2[q * 2 + 1] + dbhi * dbhi;
          }
        }
      }
      // reduction tree, identical pairing to the reference:
      // s8[j] = rr[j] + rr[j+8]  -> s8_2[m] = rr2[m] + rr2[m+4]
#pragma unroll
      for (int r = 0; r < 2; ++r) {
        const f32x2* rr2 = (r == 0) ? ra2 : rb2;
        f32x2 s8_2[4], s4_2[2], s2_2;
#pragma unroll
        for (int m = 0; m < 4; ++m) s8_2[m] = rr2[m] + rr2[m + 4];
#pragma unroll
        for (int m = 0; m < 2; ++m) s4_2[m] = s8_2[m] + s8_2[m + 2];
        s2_2 = s4_2[0] + s4_2[1];          // = (s2[0], s2[1])
        const float tot = s2_2[0] + s2_2[1];
        const float dv = (float)__builtin_sqrt((double)tot);
        const int row = 2 * h + r;
        o_d[(size_t)(r0 + row) * NU + n] = dv;
        keys[row * NU + n] = ((ull)__float_as_uint(dv) << 32) | (ull)n;
      }
    }
  }
  __syncthreads();

  // ---- per-wave stable bitonic sort of 512 keys (wave w = row w) ----
  {
    const unsigned lane = (unsigned)(t & 63);
    const int w = t >> 6;

    ull v[8];
#pragma unroll
    for (int i = 0; i < 8; ++i) v[i] = keys[w * NU + i * 64 + (int)lane];

    // pre-stages K=2,4,8 (directions compile-time / lane-bit0)
    ce(v[0], v[1], true);  ce(v[2], v[3], false);
    ce(v[4], v[5], true);  ce(v[6], v[7], false);            // K=2
    ce(v[0], v[2], true);  ce(v[1], v[3], true);
    ce(v[4], v[6], false); ce(v[5], v[7], false);            // K=4 S=2
    ce(v[0], v[1], true);  ce(v[2], v[3], true);
    ce(v[4], v[5], false); ce(v[6], v[7], false);            // K=4 S=1
    {
      const bool a8 = ((lane & 1u) == 0u);                   // K=8
      ce(v[0], v[4], a8); ce(v[1], v[5], a8); ce(v[2], v[6], a8); ce(v[3], v[7], a8);
      ce(v[0], v[2], a8); ce(v[1], v[3], a8); ce(v[4], v[6], a8); ce(v[5], v[7], a8);
      ce(v[0], v[1], a8); ce(v[2], v[3], a8); ce(v[4], v[5], a8); ce(v[6], v[7], a8);
    }

    const int ad4  = (int)((lane ^ 4u)  << 2);
    const int ad8  = (int)((lane ^ 8u)  << 2);
    const int ad16 = (int)((lane ^ 16u) << 2);
    const int ad32 = (int)((lane ^ 32u) << 2);
    stage_t<16>(v, lane, ad4, ad8, ad16, ad32);
    stage_t<32>(v, lane, ad4, ad8, ad16, ad32);
    stage_t<64>(v, lane, ad4, ad8, ad16, ad32);
    stage_t<128>(v, lane, ad4, ad8, ad16, ad32);
    stage_t<256>(v, lane, ad4, ad8, ad16, ad32);
    stage_t<512>(v, lane, ad4, ad8, ad16, ad32);

    const int row = r0 + w;
    float* o_is = out + (size_t)B_ROWS * NU;
    float* o_k  = o_is + (size_t)B_ROWS * NU;
    float* o_z  = o_k + (size_t)B_ROWS * NU;
    float* o_xc = o_z + (size_t)B_ROWS * NU;

    int idxv[8];
#pragma unroll
    for (int i = 0; i < 8; ++i) idxv[i] = (int)(v[i] & 0x1ffULL);

    // i_sort: coalesced float4 stores
    float4 fa, fb;
    fa.x = (float)idxv[0]; fa.y = (float)idxv[1];
    fa.z = (float)idxv[2]; fa.w = (float)idxv[3];
    fb.x = (float)idxv[4]; fb.y = (float)idxv[5];
    fb.z = (float)idxv[6]; fb.w = (float)idxv[7];
    float4* isrow = (float4*)(o_is + (size_t)row * NU);
    isrow[lane * 2 + 0] = fa;
    isrow[lane * 2 + 1] = fb;

    // ---- inverse permutation in LDS (wave-private row) ----
    // rank of original index idxv[i] is e = lane*8 + i
#pragma unroll
    for (int i = 0; i < 8; ++i)
      rks[w * NU + idxv[i]] = (unsigned short)((int)lane * 8 + i);

    // lane l (l<8) holds zval = 1/(l+1); recovered per-element via bpermute.
    // Constants fold identically to 1.0f/(float)(i+1) (IEEE round-to-nearest).
    const unsigned l8 = lane & 7u;
    const float v00 = (l8 & 1u) ? 0.5f : 1.0f;
    const float v01 = (l8 & 1u) ? 0.25f : (1.0f / 3.0f);
    const float v10 = (l8 & 1u) ? (1.0f / 6.0f) : 0.2f;
    const float v11 = (l8 & 1u) ? 0.125f : (1.0f / 7.0f);
    const float va  = (l8 & 2u) ? v01 : v00;
    const float vb  = (l8 & 2u) ? v11 : v10;
    const float zv  = (l8 & 4u) ? vb : va;
    const int zvb = __float_as_int(zv);

    // lane-contiguous rank read: 8 u16 = one ds_read_b128, then float4 stores
    const ushort8 ev = *(const ushort8*)(&rks[w * NU + (int)lane * 8]);
    int e[8];
#pragma unroll
    for (int i = 0; i < 8; ++i) e[i] = (int)ev[i];

    float4 k0, k1, z0, z1;
    k0.x = (float)e[0]; k0.y = (float)e[1]; k0.z = (float)e[2]; k0.w = (float)e[3];
    k1.x = (float)e[4]; k1.y = (float)e[5]; k1.z = (float)e[6]; k1.w = (float)e[7];
    float zt[8];
#pragma unroll
    for (int i = 0; i < 8; ++i) {
      const int zb = __builtin_amdgcn_ds_bpermute((e[i] & 63) << 2, zvb);
      zt[i] = (e[i] < TOPK_K) ? __int_as_float(zb) : 0.0f;
    }
    z0.x = zt[0]; z0.y = zt[1]; z0.z = zt[2]; z0.w = zt[3];
    z1.x = zt[4]; z1.y = zt[5]; z1.z = zt[6]; z1.w = zt[7];

    float4* krow = (float4*)(o_k + (size_t)row * NU + (size_t)lane * 8);
    float4* zrow = (float4*)(o_z + (size_t)row * NU + (size_t)lane * 8);
    krow[0] = k0; krow[1] = k1;
    zrow[0] = z0; zrow[1] = z1;

    int top = idxv[0];
    top = __shfl(top, 0, 64);
    o_xc[(size_t)row * FEATS + (int)lane] = c[top * FEATS + (int)lane];
  }
}

extern "C" void kernel_launch(void* const* d_in, const int* in_sizes, int n_in,
                              void* d_out, int out_size, void* d_ws, size_t ws_size,
                              hipStream_t stream) {
  const float* x = (const float*)d_in[0];
  const float* c = (const float*)d_in[1];
  float* out = (float*)d_out;
  lcm_kernel<<<dim3(B_ROWS / RPB), dim3(512), 0, stream>>>(x, c, out);
}

// Round 10
// 217.683 us; speedup vs baseline: 1.0577x; 1.0577x over previous
//
#include <hip/hip_runtime.h>
#include <math.h>

#define B_ROWS 8192
#define NU 512
#define FEATS 64
#define RPB 8      // rows per block (= waves per block)
#define TOPK_K 8

typedef unsigned long long ull;
typedef unsigned short ushort8 __attribute__((ext_vector_type(8)));
typedef float f32x2 __attribute__((ext_vector_type(2)));

// xor-1 / xor-2 lane exchange via DPP quad_perm (VALU pipe, no DS)
template <int CTRL>
__device__ __forceinline__ ull dpp_u64(ull x) {
  int lo = (int)(unsigned)(x & 0xffffffffULL);
  int hi = (int)(unsigned)(x >> 32);
  lo = __builtin_amdgcn_update_dpp(lo, lo, CTRL, 0xf, 0xf, true);
  hi = __builtin_amdgcn_update_dpp(hi, hi, CTRL, 0xf, 0xf, true);
  return ((ull)(unsigned)hi << 32) | (ull)(unsigned)lo;
}

__device__ __forceinline__ ull bperm_u64(int addr, ull x) {
  int lo = (int)(unsigned)(x & 0xffffffffULL);
  int hi = (int)(unsigned)(x >> 32);
  lo = __builtin_amdgcn_ds_bpermute(addr, lo);
  hi = __builtin_amdgcn_ds_bpermute(addr, hi);
  return ((ull)(unsigned)hi << 32) | (ull)(unsigned)lo;
}

// compare-exchange: after call, (a,b) ordered ascending iff asc
__device__ __forceinline__ void ce(ull& a, ull& b, bool asc) {
  const bool lt = a < b;
  const bool sw = (lt != asc);
  const ull t = sw ? b : a;
  b = sw ? a : b;
  a = t;
}

// cross-lane pass: lane-xor M, merge-size direction bit KB = K>>3
template <unsigned M, unsigned KB>
__device__ __forceinline__ void cross_t(ull v[8], unsigned lane, int addr) {
  const bool asc = ((lane & KB) == 0u);
  const bool takeMin = (((lane & M) == 0u) == asc);
#pragma unroll
  for (int i = 0; i < 8; ++i) {
    ull o;
    if constexpr (M == 1)      o = dpp_u64<0xB1>(v[i]);   // quad_perm [1,0,3,2]
    else if constexpr (M == 2) o = dpp_u64<0x4E>(v[i]);   // quad_perm [2,3,0,1]
    else                       o = bperm_u64(addr, v[i]);
    const bool keep = ((v[i] < o) == takeMin);
    v[i] = keep ? v[i] : o;
  }
}

// one bitonic merge stage of size K (16..512), fully compile-time unrolled
template <unsigned K>
__device__ __forceinline__ void stage_t(ull v[8], unsigned lane,
                                        int a4, int a8, int a16, int a32) {
  constexpr unsigned KB = (K >> 3);
  if constexpr (K >= 512) cross_t<32, KB>(v, lane, a32);
  if constexpr (K >= 256) cross_t<16, KB>(v, lane, a16);
  if constexpr (K >= 128) cross_t<8,  KB>(v, lane, a8);
  if constexpr (K >= 64)  cross_t<4,  KB>(v, lane, a4);
  if constexpr (K >= 32)  cross_t<2,  KB>(v, lane, 0);
  cross_t<1, KB>(v, lane, 0);
  const bool asc = ((lane & KB) == 0u);
  ce(v[0], v[4], asc); ce(v[1], v[5], asc); ce(v[2], v[6], asc); ce(v[3], v[7], asc);
  ce(v[0], v[2], asc); ce(v[1], v[3], asc); ce(v[4], v[6], asc); ce(v[5], v[7], asc);
  ce(v[0], v[1], asc); ce(v[2], v[3], asc); ce(v[4], v[5], asc); ce(v[6], v[7], asc);
}

// Evidence ledger:
//  r1/r6 (thread-per-unit, remat'd c): 57.6 us. r6 f32x2 packing cut VALU-issue
//      39->29 us, wall flat => not VALU-bound; memory pipes + coupling remain.
//  r2/r5/r7: ALL register-pinning variants lose (vol. pins serialize VMEM: 104us;
//      nonvol. pins shrink alloc to 40 VGPR: 105us). Pinning is dead.
//  r3: >64 live regs spills (+30 MB scratch HBM): 65us.
//  r8: clean 2-row tile took 68 VGPR -> crossed the 64-reg occupancy cliff
//      (waves/SIMD halve): occupancy 35->23%, 178us. Budget is HARD <=64.
//  => This version: WAVE-PER-ROW remap. Wave w computes all 512 units of its
//     row. c-load count is unchanged (each wave reads all of c once), but:
//     x loads become wave-uniform -> scalar/SMEM path (-32 VMEM/thread);
//     the keys LDS round-trip is thread-local (same address write->read);
//     keys/rks are wave-private so __syncthreads() is DELETED -- waves
//     decouple and phase tails overlap across the CU.
//     launch_bounds(512,8) pins the 64-VGPR budget (r8 guard).
//     Per-(row,unit) arithmetic identical to r6 -> bitwise-identical outputs.
__global__ __launch_bounds__(512, 8)
void lcm_kernel(const float* __restrict__ x, const float* __restrict__ c,
                float* __restrict__ out) {
#pragma clang fp contract(off)
  __shared__ ull keys[RPB * NU];                          // 32 KB (wave-private rows)
  __shared__ __align__(16) unsigned short rks[RPB * NU];  // 8 KB (40 KB total -> 4 blocks/CU)

  const int t = threadIdx.x;
  const unsigned lane = (unsigned)(t & 63);
  const int w = t >> 6;
  const int r0 = blockIdx.x * RPB;
  // wave-uniform row index, forced into an SGPR so x loads get the scalar path
  const int row = __builtin_amdgcn_readfirstlane(r0 + w);

  // ---- phase 1: wave w computes all 512 units of its row ----
  {
    const float* __restrict__ xr = x + (size_t)row * FEATS;  // uniform (SGPR addr)
    float* o_d = out;

#pragma unroll
    for (int i = 0; i < 8; ++i) {
      const int u = i * 64 + (int)lane;
      const float4* cu = (const float4*)c + (size_t)u * 16;
      // rr2[m] = (rr[2m], rr[2m+1]) of the reference's rr[16]
      f32x2 rr2[8];
#pragma unroll
      for (int k = 0; k < 4; ++k) {
#pragma unroll
        for (int q = 0; q < 4; ++q) {
          const float4 cv = cu[k * 4 + q];                      // consumed once
          const float4 xv = *(const float4*)(xr + 16 * k + 4 * q);  // uniform
          f32x2 xlo, xhi, clo, chi;
          xlo[0] = xv.x; xlo[1] = xv.y; xhi[0] = xv.z; xhi[1] = xv.w;
          clo[0] = cv.x; clo[1] = cv.y; chi[0] = cv.z; chi[1] = cv.w;
          const f32x2 dlo = xlo - clo;   // v_pk ops, IEEE per element
          const f32x2 dhi = xhi - chi;
          if (k == 0) {
            rr2[q * 2 + 0] = dlo * dlo;
            rr2[q * 2 + 1] = dhi * dhi;
          } else {
            rr2[q * 2 + 0] = rr2[q * 2 + 0] + dlo * dlo;
            rr2[q * 2 + 1] = rr2[q * 2 + 1] + dhi * dhi;
          }
        }
      }
      // reduction tree, identical pairing to the reference
      f32x2 s8_2[4], s4_2[2], s2_2;
#pragma unroll
      for (int m = 0; m < 4; ++m) s8_2[m] = rr2[m] + rr2[m + 4];
#pragma unroll
      for (int m = 0; m < 2; ++m) s4_2[m] = s8_2[m] + s8_2[m + 2];
      s2_2 = s4_2[0] + s4_2[1];          // = (s2[0], s2[1])
      const float tot = s2_2[0] + s2_2[1];
      const float dv = (float)__builtin_sqrt((double)tot);
      o_d[(size_t)row * NU + u] = dv;                    // coalesced 256B/wave
      keys[w * NU + u] = ((ull)__float_as_uint(dv) << 32) | (ull)u;
    }
  }
  // NO __syncthreads(): keys/rks regions are wave-private; within-wave
  // ds_write -> ds_read ordering is enforced by lgkmcnt.

  // ---- per-wave stable bitonic sort of 512 keys (wave w = row w) ----
  {
    ull v[8];
#pragma unroll
    for (int i = 0; i < 8; ++i) v[i] = keys[w * NU + i * 64 + (int)lane];

    // pre-stages K=2,4,8 (directions compile-time / lane-bit0)
    ce(v[0], v[1], true);  ce(v[2], v[3], false);
    ce(v[4], v[5], true);  ce(v[6], v[7], false);            // K=2
    ce(v[0], v[2], true);  ce(v[1], v[3], true);
    ce(v[4], v[6], false); ce(v[5], v[7], false);            // K=4 S=2
    ce(v[0], v[1], true);  ce(v[2], v[3], true);
    ce(v[4], v[5], false); ce(v[6], v[7], false);            // K=4 S=1
    {
      const bool a8 = ((lane & 1u) == 0u);                   // K=8
      ce(v[0], v[4], a8); ce(v[1], v[5], a8); ce(v[2], v[6], a8); ce(v[3], v[7], a8);
      ce(v[0], v[2], a8); ce(v[1], v[3], a8); ce(v[4], v[6], a8); ce(v[5], v[7], a8);
      ce(v[0], v[1], a8); ce(v[2], v[3], a8); ce(v[4], v[5], a8); ce(v[6], v[7], a8);
    }

    const int ad4  = (int)((lane ^ 4u)  << 2);
    const int ad8  = (int)((lane ^ 8u)  << 2);
    const int ad16 = (int)((lane ^ 16u) << 2);
    const int ad32 = (int)((lane ^ 32u) << 2);
    stage_t<16>(v, lane, ad4, ad8, ad16, ad32);
    stage_t<32>(v, lane, ad4, ad8, ad16, ad32);
    stage_t<64>(v, lane, ad4, ad8, ad16, ad32);
    stage_t<128>(v, lane, ad4, ad8, ad16, ad32);
    stage_t<256>(v, lane, ad4, ad8, ad16, ad32);
    stage_t<512>(v, lane, ad4, ad8, ad16, ad32);

    float* o_is = out + (size_t)B_ROWS * NU;
    float* o_k  = o_is + (size_t)B_ROWS * NU;
    float* o_z  = o_k + (size_t)B_ROWS * NU;
    float* o_xc = o_z + (size_t)B_ROWS * NU;

    int idxv[8];
#pragma unroll
    for (int i = 0; i < 8; ++i) idxv[i] = (int)(v[i] & 0x1ffULL);

    // i_sort: coalesced float4 stores
    float4 fa, fb;
    fa.x = (float)idxv[0]; fa.y = (float)idxv[1];
    fa.z = (float)idxv[2]; fa.w = (float)idxv[3];
    fb.x = (float)idxv[4]; fb.y = (float)idxv[5];
    fb.z = (float)idxv[6]; fb.w = (float)idxv[7];
    float4* isrow = (float4*)(o_is + (size_t)row * NU);
    isrow[lane * 2 + 0] = fa;
    isrow[lane * 2 + 1] = fb;

    // ---- inverse permutation in LDS (wave-private row) ----
    // rank of original index idxv[i] is e = lane*8 + i
#pragma unroll
    for (int i = 0; i < 8; ++i)
      rks[w * NU + idxv[i]] = (unsigned short)((int)lane * 8 + i);

    // lane l (l<8) holds zval = 1/(l+1); recovered per-element via bpermute.
    // Constants fold identically to 1.0f/(float)(i+1) (IEEE round-to-nearest).
    const unsigned l8 = lane & 7u;
    const float v00 = (l8 & 1u) ? 0.5f : 1.0f;
    const float v01 = (l8 & 1u) ? 0.25f : (1.0f / 3.0f);
    const float v10 = (l8 & 1u) ? (1.0f / 6.0f) : 0.2f;
    const float v11 = (l8 & 1u) ? 0.125f : (1.0f / 7.0f);
    const float va  = (l8 & 2u) ? v01 : v00;
    const float vb  = (l8 & 2u) ? v11 : v10;
    const float zv  = (l8 & 4u) ? vb : va;
    const int zvb = __float_as_int(zv);

    // lane-contiguous rank read: 8 u16 = one ds_read_b128, then float4 stores
    const ushort8 ev = *(const ushort8*)(&rks[w * NU + (int)lane * 8]);
    int e[8];
#pragma unroll
    for (int i = 0; i < 8; ++i) e[i] = (int)ev[i];

    float4 k0, k1, z0, z1;
    k0.x = (float)e[0]; k0.y = (float)e[1]; k0.z = (float)e[2]; k0.w = (float)e[3];
    k1.x = (float)e[4]; k1.y = (float)e[5]; k1.z = (float)e[6]; k1.w = (float)e[7];
    float zt[8];
#pragma unroll
    for (int i = 0; i < 8; ++i) {
      const int zb = __builtin_amdgcn_ds_bpermute((e[i] & 63) << 2, zvb);
      zt[i] = (e[i] < TOPK_K) ? __int_as_float(zb) : 0.0f;
    }
    z0.x = zt[0]; z0.y = zt[1]; z0.z = zt[2]; z0.w = zt[3];
    z1.x = zt[4]; z1.y = zt[5]; z1.z = zt[6]; z1.w = zt[7];

    float4* krow = (float4*)(o_k + (size_t)row * NU + (size_t)lane * 8);
    float4* zrow = (float4*)(o_z + (size_t)row * NU + (size_t)lane * 8);
    krow[0] = k0; krow[1] = k1;
    zrow[0] = z0; zrow[1] = z1;

    int top = idxv[0];
    top = __shfl(top, 0, 64);
    o_xc[(size_t)row * FEATS + (int)lane] = c[top * FEATS + (int)lane];
  }
}

extern "C" void kernel_launch(void* const* d_in, const int* in_sizes, int n_in,
                              void* d_out, int out_size, void* d_ws, size_t ws_size,
                              hipStream_t stream) {
  const float* x = (const float*)d_in[0];
  const float* c = (const float*)d_in[1];
  float* out = (float*)d_out;
  lcm_kernel<<<dim3(B_ROWS / RPB), dim3(512), 0, stream>>>(x, c, out);
}

// Round 11
// 122.314 us; speedup vs baseline: 1.8824x; 1.7797x over previous
//
#include <hip/hip_runtime.h>
#include <math.h>

#define B_ROWS 8192
#define NU 512
#define FEATS 64
#define RPB 8      // rows per block (= waves per block)
#define TOPK_K 8

typedef unsigned long long ull;
typedef unsigned short ushort8 __attribute__((ext_vector_type(8)));
typedef float f32x2 __attribute__((ext_vector_type(2)));

// xor-1 / xor-2 lane exchange via DPP quad_perm (VALU pipe, no DS)
template <int CTRL>
__device__ __forceinline__ ull dpp_u64(ull x) {
  int lo = (int)(unsigned)(x & 0xffffffffULL);
  int hi = (int)(unsigned)(x >> 32);
  lo = __builtin_amdgcn_update_dpp(lo, lo, CTRL, 0xf, 0xf, true);
  hi = __builtin_amdgcn_update_dpp(hi, hi, CTRL, 0xf, 0xf, true);
  return ((ull)(unsigned)hi << 32) | (ull)(unsigned)lo;
}

__device__ __forceinline__ ull bperm_u64(int addr, ull x) {
  int lo = (int)(unsigned)(x & 0xffffffffULL);
  int hi = (int)(unsigned)(x >> 32);
  lo = __builtin_amdgcn_ds_bpermute(addr, lo);
  hi = __builtin_amdgcn_ds_bpermute(addr, hi);
  return ((ull)(unsigned)hi << 32) | (ull)(unsigned)lo;
}

// compare-exchange: after call, (a,b) ordered ascending iff asc
__device__ __forceinline__ void ce(ull& a, ull& b, bool asc) {
  const bool lt = a < b;
  const bool sw = (lt != asc);
  const ull t = sw ? b : a;
  b = sw ? a : b;
  a = t;
}

// cross-lane pass: lane-xor M, merge-size direction bit KB = K>>3
template <unsigned M, unsigned KB>
__device__ __forceinline__ void cross_t(ull v[8], unsigned lane, int addr) {
  const bool asc = ((lane & KB) == 0u);
  const bool takeMin = (((lane & M) == 0u) == asc);
#pragma unroll
  for (int i = 0; i < 8; ++i) {
    ull o;
    if constexpr (M == 1)      o = dpp_u64<0xB1>(v[i]);   // quad_perm [1,0,3,2]
    else if constexpr (M == 2) o = dpp_u64<0x4E>(v[i]);   // quad_perm [2,3,0,1]
    else                       o = bperm_u64(addr, v[i]);
    const bool keep = ((v[i] < o) == takeMin);
    v[i] = keep ? v[i] : o;
  }
}

// one bitonic merge stage of size K (16..512), fully compile-time unrolled
template <unsigned K>
__device__ __forceinline__ void stage_t(ull v[8], unsigned lane,
                                        int a4, int a8, int a16, int a32) {
  constexpr unsigned KB = (K >> 3);
  if constexpr (K >= 512) cross_t<32, KB>(v, lane, a32);
  if constexpr (K >= 256) cross_t<16, KB>(v, lane, a16);
  if constexpr (K >= 128) cross_t<8,  KB>(v, lane, a8);
  if constexpr (K >= 64)  cross_t<4,  KB>(v, lane, a4);
  if constexpr (K >= 32)  cross_t<2,  KB>(v, lane, 0);
  cross_t<1, KB>(v, lane, 0);
  const bool asc = ((lane & KB) == 0u);
  ce(v[0], v[4], asc); ce(v[1], v[5], asc); ce(v[2], v[6], asc); ce(v[3], v[7], asc);
  ce(v[0], v[2], asc); ce(v[1], v[3], asc); ce(v[4], v[6], asc); ce(v[5], v[7], asc);
  ce(v[0], v[1], asc); ce(v[2], v[3], asc); ce(v[4], v[5], asc); ce(v[6], v[7], asc);
}

// Evidence ledger:
//  r1/r6 (thread-per-unit, per-lane c from global): 57.6 us floor. r6 showed
//      VALU-issue is only 29 us -> residual is the UNCOALESCED c path (each
//      wave dwordx4 touches 64 lines; TA line-serialization ~50 us).
//  r2/r5/r7 (pins), r3/r8 (>64 VGPR), r10 (launch_bounds(512,8) -> 32 VGPR +
//      24 MB scratch): all register/occupancy directives fail. Plain
//      __launch_bounds__(512) only.
//  r10 also PROVED correctness of wave-per-row + no-barrier wave-private
//      epilogue (absmax 0.0).
//  => This version: wave-per-row compute + block-shared COALESCED c staging.
//     Per chunk of 64 units: block stages the 16 KB c-tile into LDS with
//     coalesced dwordx4 (16 loads/thread total vs 128 uncoalesced), XOR-swizzle
//     f4idx ^ ((f4idx>>4)&7) on write AND read (G4 fix for 256B-row b128
//     conflicts). Keys never touch LDS: chunk i's distance IS v[i] (sort
//     layout is native to wave-per-row). LDS = 2x16KB ctile + 8KB rks = 40KB.
//     Arithmetic is r6's f32x2 body verbatim -> bitwise-identical outputs.
__global__ __launch_bounds__(512)
void lcm_kernel(const float* __restrict__ x, const float* __restrict__ c,
                float* __restrict__ out) {
#pragma clang fp contract(off)
  __shared__ float ctile[2][64 * 64];                     // 2 x 16 KB
  __shared__ __align__(16) unsigned short rks[RPB * NU];  // 8 KB (40 KB total)

  const int t = threadIdx.x;
  const unsigned lane = (unsigned)(t & 63);
  const int w = t >> 6;
  const int r0 = blockIdx.x * RPB;
  // wave-uniform row index in SGPR -> x loads take the scalar/SMEM path (r10)
  const int row = __builtin_amdgcn_readfirstlane(r0 + w);
  const float* __restrict__ xr = x + (size_t)row * FEATS;

  const float4* __restrict__ cg = (const float4*)c;
  float4* ct0 = (float4*)&ctile[0][0];
  float4* ct1 = (float4*)&ctile[1][0];

  ull v[8];

  // prologue: stage chunk 0 into buf 0 (coalesced; swizzled dest)
  {
    const int i0 = t, i1 = t + 512;
    ct0[i0 ^ ((i0 >> 4) & 7)] = cg[i0];
    ct0[i1 ^ ((i1 >> 4) & 7)] = cg[i1];
  }
  __syncthreads();

  float* o_d = out;
#pragma unroll
  for (int ch = 0; ch < 8; ++ch) {
    // stage chunk ch+1 into the other buffer (overlaps with compute below)
    if (ch < 7) {
      const int g0 = (ch + 1) * 1024 + t, g1 = g0 + 512;
      const int i0 = t, i1 = t + 512;
      float4* dst = (ch & 1) ? ct0 : ct1;  // buffer (ch+1)&1
      dst[i0 ^ ((i0 >> 4) & 7)] = cg[g0];
      dst[i1 ^ ((i1 >> 4) & 7)] = cg[g1];
    }
    // compute unit u = ch*64 + lane for this wave's row, from buffer ch&1
    const float4* src = (ch & 1) ? ct1 : ct0;
    f32x2 rr2[8];
#pragma unroll
    for (int k = 0; k < 4; ++k) {
#pragma unroll
      for (int q = 0; q < 4; ++q) {
        const int idx = (int)lane * 16 + k * 4 + q;
        const float4 cv = src[idx ^ ((idx >> 4) & 7)];           // swizzled read
        const float4 xv = *(const float4*)(xr + 16 * k + 4 * q); // uniform/SMEM
        f32x2 xlo, xhi, clo, chi;
        xlo[0] = xv.x; xlo[1] = xv.y; xhi[0] = xv.z; xhi[1] = xv.w;
        clo[0] = cv.x; clo[1] = cv.y; chi[0] = cv.z; chi[1] = cv.w;
        const f32x2 dlo = xlo - clo;   // v_pk ops, IEEE per element
        const f32x2 dhi = xhi - chi;
        if (k == 0) {
          rr2[q * 2 + 0] = dlo * dlo;
          rr2[q * 2 + 1] = dhi * dhi;
        } else {
          rr2[q * 2 + 0] = rr2[q * 2 + 0] + dlo * dlo;
          rr2[q * 2 + 1] = rr2[q * 2 + 1] + dhi * dhi;
        }
      }
    }
    // reduction tree, identical pairing to the reference
    f32x2 s8_2[4], s4_2[2], s2_2;
#pragma unroll
    for (int m = 0; m < 4; ++m) s8_2[m] = rr2[m] + rr2[m + 4];
#pragma unroll
    for (int m = 0; m < 2; ++m) s4_2[m] = s8_2[m] + s8_2[m + 2];
    s2_2 = s4_2[0] + s4_2[1];          // = (s2[0], s2[1])
    const float tot = s2_2[0] + s2_2[1];
    const float dv = (float)__builtin_sqrt((double)tot);
    const int u = ch * 64 + (int)lane;
    o_d[(size_t)row * NU + u] = dv;    // coalesced 256B/wave
    v[ch] = ((ull)__float_as_uint(dv) << 32) | (ull)u;  // key in register
    if (ch < 7) __syncthreads();       // reads of buf done before it's rewritten
  }

  // ---- per-wave stable bitonic sort of 512 keys (wave w = row w) ----
  {
    // pre-stages K=2,4,8 (directions compile-time / lane-bit0)
    ce(v[0], v[1], true);  ce(v[2], v[3], false);
    ce(v[4], v[5], true);  ce(v[6], v[7], false);            // K=2
    ce(v[0], v[2], true);  ce(v[1], v[3], true);
    ce(v[4], v[6], false); ce(v[5], v[7], false);            // K=4 S=2
    ce(v[0], v[1], true);  ce(v[2], v[3], true);
    ce(v[4], v[5], false); ce(v[6], v[7], false);            // K=4 S=1
    {
      const bool a8 = ((lane & 1u) == 0u);                   // K=8
      ce(v[0], v[4], a8); ce(v[1], v[5], a8); ce(v[2], v[6], a8); ce(v[3], v[7], a8);
      ce(v[0], v[2], a8); ce(v[1], v[3], a8); ce(v[4], v[6], a8); ce(v[5], v[7], a8);
      ce(v[0], v[1], a8); ce(v[2], v[3], a8); ce(v[4], v[5], a8); ce(v[6], v[7], a8);
    }

    const int ad4  = (int)((lane ^ 4u)  << 2);
    const int ad8  = (int)((lane ^ 8u)  << 2);
    const int ad16 = (int)((lane ^ 16u) << 2);
    const int ad32 = (int)((lane ^ 32u) << 2);
    stage_t<16>(v, lane, ad4, ad8, ad16, ad32);
    stage_t<32>(v, lane, ad4, ad8, ad16, ad32);
    stage_t<64>(v, lane, ad4, ad8, ad16, ad32);
    stage_t<128>(v, lane, ad4, ad8, ad16, ad32);
    stage_t<256>(v, lane, ad4, ad8, ad16, ad32);
    stage_t<512>(v, lane, ad4, ad8, ad16, ad32);

    float* o_is = out + (size_t)B_ROWS * NU;
    float* o_k  = o_is + (size_t)B_ROWS * NU;
    float* o_z  = o_k + (size_t)B_ROWS * NU;
    float* o_xc = o_z + (size_t)B_ROWS * NU;

    int idxv[8];
#pragma unroll
    for (int i = 0; i < 8; ++i) idxv[i] = (int)(v[i] & 0x1ffULL);

    // i_sort: coalesced float4 stores
    float4 fa, fb;
    fa.x = (float)idxv[0]; fa.y = (float)idxv[1];
    fa.z = (float)idxv[2]; fa.w = (float)idxv[3];
    fb.x = (float)idxv[4]; fb.y = (float)idxv[5];
    fb.z = (float)idxv[6]; fb.w = (float)idxv[7];
    float4* isrow = (float4*)(o_is + (size_t)row * NU);
    isrow[lane * 2 + 0] = fa;
    isrow[lane * 2 + 1] = fb;

    // ---- inverse permutation in LDS (wave-private region, no barrier) ----
    // rank of original index idxv[i] is e = lane*8 + i
#pragma unroll
    for (int i = 0; i < 8; ++i)
      rks[w * NU + idxv[i]] = (unsigned short)((int)lane * 8 + i);

    // lane l (l<8) holds zval = 1/(l+1); recovered per-element via bpermute.
    // Constants fold identically to 1.0f/(float)(i+1) (IEEE round-to-nearest).
    const unsigned l8 = lane & 7u;
    const float v00 = (l8 & 1u) ? 0.5f : 1.0f;
    const float v01 = (l8 & 1u) ? 0.25f : (1.0f / 3.0f);
    const float v10 = (l8 & 1u) ? (1.0f / 6.0f) : 0.2f;
    const float v11 = (l8 & 1u) ? 0.125f : (1.0f / 7.0f);
    const float va  = (l8 & 2u) ? v01 : v00;
    const float vb  = (l8 & 2u) ? v11 : v10;
    const float zv  = (l8 & 4u) ? vb : va;
    const int zvb = __float_as_int(zv);

    // lane-contiguous rank read: 8 u16 = one ds_read_b128, then float4 stores
    const ushort8 ev = *(const ushort8*)(&rks[w * NU + (int)lane * 8]);
    int e[8];
#pragma unroll
    for (int i = 0; i < 8; ++i) e[i] = (int)ev[i];

    float4 k0, k1, z0, z1;
    k0.x = (float)e[0]; k0.y = (float)e[1]; k0.z = (float)e[2]; k0.w = (float)e[3];
    k1.x = (float)e[4]; k1.y = (float)e[5]; k1.z = (float)e[6]; k1.w = (float)e[7];
    float zt[8];
#pragma unroll
    for (int i = 0; i < 8; ++i) {
      const int zb = __builtin_amdgcn_ds_bpermute((e[i] & 63) << 2, zvb);
      zt[i] = (e[i] < TOPK_K) ? __int_as_float(zb) : 0.0f;
    }
    z0.x = zt[0]; z0.y = zt[1]; z0.z = zt[2]; z0.w = zt[3];
    z1.x = zt[4]; z1.y = zt[5]; z1.z = zt[6]; z1.w = zt[7];

    float4* krow = (float4*)(o_k + (size_t)row * NU + (size_t)lane * 8);
    float4* zrow = (float4*)(o_z + (size_t)row * NU + (size_t)lane * 8);
    krow[0] = k0; krow[1] = k1;
    zrow[0] = z0; zrow[1] = z1;

    int top = idxv[0];
    top = __shfl(top, 0, 64);
    o_xc[(size_t)row * FEATS + (int)lane] = c[top * FEATS + (int)lane];
  }
}

extern "C" void kernel_launch(void* const* d_in, const int* in_sizes, int n_in,
                              void* d_out, int out_size, void* d_ws, size_t ws_size,
                              hipStream_t stream) {
  const float* x = (const float*)d_in[0];
  const float* c = (const float*)d_in[1];
  float* out = (float*)d_out;
  lcm_kernel<<<dim3(B_ROWS / RPB), dim3(512), 0, stream>>>(x, c, out);
}